// Round 6
// baseline (36.409 us; speedup 1.0000x reference)
//
#include <hip/hip_runtime.h>
#include <math.h>
#include <utility>

// EPG simulation, TWO pixels per thread, packed-f32 (v2f lane = pixel).
// State invariant per pixel: F+ = i*fp, F- = i*fm (pure imaginary), Z real.
// The two pixels never interact -> shift stays register renaming, no shuffles;
// <2 x float> fma selects v_pk_fma_f32 on gfx950 (2x issue) and doubles the
// independent dep-chains per instruction stream (hides VALU latency at 2
// waves/SIMD).
//
// Double-sided band: rotation band A(t) = min(t, KMAX, 31-t) <= 15
//   forward:  slots > t still exactly 0
//   backward: slot k entering step t only influences echoes t' >= t+k
// In-place rolling update (j = A down to 0, rm_prev 1-slot history):
//   rp,rm,zn from (fp,fm,z)[j]; fp[j+1]=rp, fm[j]=rm_prev, z[j]=zn
//   then fp[0]=fm[0] (S[0:2,4]=1 quirk), z[0]+=inj.
// Echoes in a 4-entry v2f ring -> one global_store_dwordx4 per pixel per 4
// steps (R4's best-measured store pattern).

#define NPULSES 32
#define KMAX 17
#define NSLOT 16   // active slots 0..15 (A <= 15 always)

typedef float v2f __attribute__((ext_vector_type(2)));

__host__ __device__ constexpr int cmin3(int a, int b, int c) {
    int m = a < b ? a : b; return m < c ? m : c;
}

template <typename F, int... Ts>
__device__ __forceinline__ void static_for(F&& f, std::integer_sequence<int, Ts...>) {
    (f(std::integral_constant<int, Ts>{}), ...);
}

__device__ __forceinline__ v2f fma2(v2f a, v2f b, v2f c) {
    return __builtin_elementwise_fma(a, b, c);
}

__global__ __launch_bounds__(256) void epg_kernel(
    const float* __restrict__ qm,   // (3, npix) flattened
    const int* __restrict__ tr_ptr, // scalar TR
    float* __restrict__ out,        // (npix, 32)
    int npix)
{
    const int tid = threadIdx.x;
    const int l = tid & 63, w = tid >> 6;
    const int pixA = blockIdx.x * 512 + w * 128 + l;   // wave covers 128 pixels
    if (pixA >= npix) return;
    const bool hasB = (pixA + 64) < npix;
    const int pixB = hasB ? pixA + 64 : pixA;

    float TR = (float)(*tr_ptr);

    v2f PD  = { qm[pixA], qm[pixB] };
    v2f T1  = { fmaf(qm[npix + pixA], 5000.0f, 0.01f),
                fmaf(qm[npix + pixB], 5000.0f, 0.01f) };
    v2f T2v = { fmaf(qm[2 * npix + pixA], 1500.0f, 0.01f),
                fmaf(qm[2 * npix + pixB], 1500.0f, 0.01f) };
    v2f E1  = { __expf(-TR / T1.x),  __expf(-TR / T1.y)  };
    v2f E2  = { __expf(-TR / T2v.x), __expf(-TR / T2v.y) };

    // RF rotation constants, alpha = pi/4, phi = 0
    const float c2 = 0.8535533905932737f;   // cos^2(pi/8)
    const float s2 = 0.1464466094067263f;   // sin^2(pi/8)
    const float sa = 0.7071067811865476f;   // sin(pi/4) == cos(pi/4)
    const v2f C2v = { c2, c2 }, S2v = { s2, s2 }, SAv = { sa, sa };

    v2f Aa  = -c2 * E2;
    v2f Bb  = -s2 * E2;
    v2f Cc  =  sa * E2;
    v2f Dd  = (0.5f * sa) * E1;
    v2f Ez  =  sa * E1;                  // E1*cos(alpha), ca == sa
    v2f inj = (1.0f - E1) * PD;          // PD folded into state scale

    v2f fp[NSLOT], fm[NSLOT], z[NSLOT];
    static_for([&](auto kc) {
        constexpr int k = decltype(kc)::value;
        fp[k] = (v2f){0.0f, 0.0f}; fm[k] = (v2f){0.0f, 0.0f}; z[k] = (v2f){0.0f, 0.0f};
    }, std::make_integer_sequence<int, NSLOT>{});
    z[0] = PD;

    float4* oA = (float4*)(out + (size_t)pixA * NPULSES);
    float4* oB = (float4*)(out + (size_t)pixB * NPULSES);
    v2f ebuf[4];

    static_for([&](auto tc) {
        constexpr int t = decltype(tc)::value;

        // echo: unscaled rotated F+_0 magnitude (E2/conj not yet folded in)
        v2f e = fma2(C2v, fp[0], fma2(S2v, fm[0], -(SAv * z[0])));
        ebuf[t & 3] = __builtin_elementwise_abs(e);
        if constexpr ((t & 3) == 3) {
            oA[t >> 2] = make_float4(ebuf[0].x, ebuf[1].x, ebuf[2].x, ebuf[3].x);
            if (hasB)
                oB[t >> 2] = make_float4(ebuf[0].y, ebuf[1].y, ebuf[2].y, ebuf[3].y);
        }

        if constexpr (t < NPULSES - 1) {
            constexpr int A = cmin3(t, KMAX, (NPULSES - 1) - t);   // <= 15
            v2f rm_prev = (v2f){0.0f, 0.0f};
            static_for([&](auto jc) {
                constexpr int j = A - decltype(jc)::value;          // A down to 0
                v2f pk = fp[j], mk = fm[j], zk = z[j];
                v2f Cz = Cc * zk;
                v2f rp = fma2(Aa, pk, fma2(Bb, mk,  Cz));
                v2f rm = fma2(Bb, pk, fma2(Aa, mk, -Cz));
                v2f zn = fma2(Ez, zk, Dd * (pk - mk));
                if constexpr (j < NSLOT - 1) fp[j + 1] = rp;        // slot16 dead
                fm[j] = rm_prev;
                z[j]  = zn;
                rm_prev = rm;
            }, std::make_integer_sequence<int, A + 1>{});
            fp[0] = fm[0];      // quirk: F+_0 and F-_0 both get rotM(slot1)
            z[0] += inj;
        }
    }, std::make_integer_sequence<int, NPULSES>{});
}

extern "C" void kernel_launch(void* const* d_in, const int* in_sizes, int n_in,
                              void* d_out, int out_size, void* d_ws, size_t ws_size,
                              hipStream_t stream) {
    const float* qm = (const float*)d_in[0];
    const int* tr = (const int*)d_in[2];   // d_in[1] = n_pulses (compile-time 32)
    float* out = (float*)d_out;
    int npix = in_sizes[0] / 3;

    int block = 256;                        // 512 pixels per block (2 px/thread)
    int grid = (npix + 511) / 512;
    epg_kernel<<<grid, block, 0, stream>>>(qm, tr, out, npix);
}

// Round 9
// 26.685 us; speedup vs baseline: 1.3644x; 1.3644x over previous
//
#include <hip/hip_runtime.h>
#include <math.h>
#include <utility>

// EPG simulation, one thread per pixel, register-resident, CODE-SIZE-OPTIMIZED.
// Hypothesis under test: prior fully-unrolled kernels (20-39 KB straight-line,
// executed once per wave, 4 waves/SIMD) are instruction-fetch bound.
// Structure: pruned unrolled head (t=0..15, ~8KB) + ROLLED tail loop
// (t=16..27: 3 iterations x 4 steps, fixed 16-slot band, ~4KB hot body)
// + pruned unrolled finale (t=28..31).
//
// State invariant: F+ = i*fp, F- = i*fm (pure imaginary), Z real.
// Band facts (verified R4-R6): rotation band A(t) = min(t, 15, 31-t);
// slots k>15 never influence any echo; dead slots (k > 31-t) may be computed
// wastefully — dead values never propagate into live slots (shift moves
// dead->dead only), and stay finite. fm[15] == 0 invariant throughout.
// In-place rolling update (j = A down to 0, rm_prev carries Rm[j+1]):
//   rp,rm,zn from (fp,fm,z)[j]; fp[j+1]=rp, fm[j]=rm_prev, z[j]=zn
//   then fp[0]=fm[0] (S[0:2,4]=1 quirk), z[0]+=inj.
// All register indices compile-time (static_for / integral_constant) -> no
// scratch. Echoes in 4-reg ring -> one global_store_dwordx4 per 4 steps.

#define NPULSES 32
#define NSLOT 16

template <typename F, int... Ts>
__device__ __forceinline__ void static_for(F&& f, std::integer_sequence<int, Ts...>) {
    (f(std::integral_constant<int, Ts>{}), ...);
}

__global__ __launch_bounds__(256) void epg_kernel(
    const float* __restrict__ qm,   // (3, npix) flattened
    const int* __restrict__ tr_ptr, // scalar TR
    float* __restrict__ out,        // (npix, 32)
    int npix)
{
    const int p = blockIdx.x * 256 + threadIdx.x;
    if (p >= npix) return;

    float PD = qm[p];
    float T1 = fmaf(qm[npix + p], 5000.0f, 0.01f);
    float T2 = fmaf(qm[2 * npix + p], 1500.0f, 0.01f);
    float TR = (float)(*tr_ptr);
    float E1 = __expf(-TR / T1);
    float E2 = __expf(-TR / T2);

    // RF rotation constants, alpha = pi/4, phi = 0
    const float c2 = 0.8535533905932737f;   // cos^2(pi/8)
    const float s2 = 0.1464466094067263f;   // sin^2(pi/8)
    const float sa = 0.7071067811865476f;   // sin(pi/4) == cos(pi/4)

    float Aa = -E2 * c2;
    float Bb = -E2 * s2;
    float Cc =  E2 * sa;
    float Dd =  E1 * 0.5f * sa;
    float Ez =  E1 * sa;                    // E1*cos(alpha), ca == sa
    float inj = (1.0f - E1) * PD;           // PD folded into state scale

    float fp[NSLOT], fm[NSLOT], z[NSLOT];
    #pragma unroll
    for (int k = 0; k < NSLOT; ++k) { fp[k] = 0.0f; fm[k] = 0.0f; z[k] = 0.0f; }
    z[0] = PD;

    float4* o4 = (float4*)(out + (size_t)p * NPULSES);
    float ebuf[4];

    // echo: unscaled rotated F+_0 magnitude (E2/conj not folded in). Static s.
    auto echo = [&](auto sc) {
        constexpr int s = decltype(sc)::value;
        float e = fmaf(c2, fp[0], fmaf(s2, fm[0], -sa * z[0]));
        ebuf[s] = fabsf(e);
    };

    // one rotation+shift over band 0..A (compile-time A), in place
    auto step_band = [&](auto Ac) {
        constexpr int A = decltype(Ac)::value;
        float rm_prev = 0.0f;    // Rm[j+1]; init = Rm[A+1] (zero or dead)
        static_for([&](auto jc) {
            constexpr int j = A - decltype(jc)::value;   // A down to 0
            float pk = fp[j], zk = z[j];
            float Cz = Cc * zk;
            if constexpr (j == NSLOT - 1) {
                // fm[15]==0 invariant; fp[16] out of band (dead) -> no rp
                float rm = fmaf(Bb, pk, -Cz);
                z[j]  = fmaf(Ez, zk, Dd * pk);
                fm[j] = rm_prev;                 // = 0, preserves invariant
                rm_prev = rm;
            } else {
                float mk = fm[j];
                float rp = fmaf(Aa, pk, fmaf(Bb, mk, Cz));
                float zn = fmaf(Ez, zk, Dd * (pk - mk));
                if constexpr (j > 0) {
                    float rm = fmaf(Bb, pk, fmaf(Aa, mk, -Cz));
                    fp[j + 1] = rp; fm[j] = rm_prev; z[j] = zn;
                    rm_prev = rm;
                } else {
                    // Rm[0] is never used by the shift
                    fp[1] = rp; fm[0] = rm_prev; z[0] = zn;
                }
            }
        }, std::make_integer_sequence<int, A + 1>{});
        fp[0] = fm[0];   // quirk: F+_0 and F-_0 both get Rm[1]
        z[0] += inj;
    };

    // ---- head: t = 0..15, pruned growing band A = t (unrolled once) ----
    static_for([&](auto tc) {
        constexpr int t = decltype(tc)::value;
        echo(std::integral_constant<int, t & 3>{});
        step_band(std::integral_constant<int, t>{});
        if constexpr ((t & 3) == 3)
            o4[t >> 2] = make_float4(ebuf[0], ebuf[1], ebuf[2], ebuf[3]);
    }, std::make_integer_sequence<int, 16>{});

    // ---- tail: t = 16..27, ROLLED (3 x 4 steps), fixed full band ----
    float4* optr = o4 + 4;
    #pragma unroll 1
    for (int it = 0; it < 3; ++it) {
        static_for([&](auto sc) {
            echo(sc);
            step_band(std::integral_constant<int, NSLOT - 1>{});
        }, std::make_integer_sequence<int, 4>{});
        *optr = make_float4(ebuf[0], ebuf[1], ebuf[2], ebuf[3]);
        ++optr;
    }

    // ---- finale: t = 28..31, pruned shrinking band (unrolled) ----
    echo(std::integral_constant<int, 0>{});
    step_band(std::integral_constant<int, 3>{});   // t=28, A=3
    echo(std::integral_constant<int, 1>{});
    step_band(std::integral_constant<int, 2>{});   // t=29, A=2
    echo(std::integral_constant<int, 2>{});
    step_band(std::integral_constant<int, 1>{});   // t=30, A=1
    echo(std::integral_constant<int, 3>{});        // t=31: echo only
    o4[7] = make_float4(ebuf[0], ebuf[1], ebuf[2], ebuf[3]);
}

extern "C" void kernel_launch(void* const* d_in, const int* in_sizes, int n_in,
                              void* d_out, int out_size, void* d_ws, size_t ws_size,
                              hipStream_t stream) {
    const float* qm = (const float*)d_in[0];
    const int* tr = (const int*)d_in[2];   // d_in[1] = n_pulses (compile-time 32)
    float* out = (float*)d_out;
    int npix = in_sizes[0] / 3;

    int block = 256;
    int grid = (npix + block - 1) / block;
    epg_kernel<<<grid, block, 0, stream>>>(qm, tr, out, npix);
}

// Round 11
// 22.744 us; speedup vs baseline: 1.6008x; 1.1733x over previous
//
#include <hip/hip_runtime.h>
#include <math.h>
#include <utility>

// EPG simulation, one thread per pixel, register-resident, PACKED-FP32.
// Adjacent k-slots packed as v2f pairs -> v_pk_fma_f32/v_pk_mul_f32 (VOP3P,
// full-rate packed FP32 on CDNA): rotation is slot-diagonal => 8 pk-ops per
// 2 slots vs 16 scalar. State stays 48 VGPRs (16 slots x 3 arrays), unlike
// R6's 2-pixel packing (96+ VGPR -> spilled). Shift (+-1 slot) = element
// re-pairing, mostly SSA renames in fully-unrolled code.
//
// State invariant: F+ = i*fp, F- = i*fm (pure imaginary), Z real.
// Band: A(t) = min(t, 15, 31-t). Pairs 0..A>>1 rotated; pair (A>>1) may
// cover slot A+1: growing phase its inputs are exact zeros (outputs 0),
// shrinking phase garbage-but-finite flowing only into dead slots (k>31-t'
// next step) — never into live slots. Coefficients |.|<1 => bounded.
// Per-slot op sequence identical to R4 => bit-identical results.
//   Cz=C*z; Rp=fma(A,p,fma(B,m,Cz)); Rm=fma(B,p,fma(A,m,-Cz));
//   Zn=fma(Ez,z,D*(p-m)); shift fp[k]=Rp[k-1], fp[0]=fm[0]=Rm[1],
//   fm[k]=Rm[k+1], z=Zn, z[0]+=inj  (S[0:2,4]=1 quirk included).

#define NPULSES 32
#define NSLOT 16
#define NPAIR 8

typedef float v2f __attribute__((ext_vector_type(2)));

__host__ __device__ constexpr int cmin3(int a, int b, int c) {
    int m = a < b ? a : b; return m < c ? m : c;
}

template <typename F, int... Ts>
__device__ __forceinline__ void static_for(F&& f, std::integer_sequence<int, Ts...>) {
    (f(std::integral_constant<int, Ts>{}), ...);
}

__device__ __forceinline__ v2f fma2(v2f a, v2f b, v2f c) {
    return __builtin_elementwise_fma(a, b, c);
}

__global__ __launch_bounds__(256) void epg_kernel(
    const float* __restrict__ qm,   // (3, npix) flattened
    const int* __restrict__ tr_ptr, // scalar TR
    float* __restrict__ out,        // (npix, 32)
    int npix)
{
    const int p = blockIdx.x * 256 + threadIdx.x;
    if (p >= npix) return;

    float PD = qm[p];
    float T1 = fmaf(qm[npix + p], 5000.0f, 0.01f);
    float T2 = fmaf(qm[2 * npix + p], 1500.0f, 0.01f);
    float TR = (float)(*tr_ptr);
    float E1 = __expf(-TR / T1);
    float E2 = __expf(-TR / T2);

    // RF rotation constants, alpha = pi/4, phi = 0
    const float c2 = 0.8535533905932737f;   // cos^2(pi/8)
    const float s2 = 0.1464466094067263f;   // sin^2(pi/8)
    const float sa = 0.7071067811865476f;   // sin(pi/4) == cos(pi/4)

    float Aa = -E2 * c2;
    float Bb = -E2 * s2;
    float Cc =  E2 * sa;
    float Dd =  E1 * 0.5f * sa;
    float Ez =  E1 * sa;                    // E1*cos(alpha), ca == sa
    float inj = (1.0f - E1) * PD;           // PD folded into state scale

    const v2f Aa2 = { Aa, Aa }, Bb2 = { Bb, Bb }, Cc2 = { Cc, Cc };
    const v2f Dd2 = { Dd, Dd }, Ez2 = { Ez, Ez };

    v2f FP[NPAIR], FM[NPAIR], Z[NPAIR];
    #pragma unroll
    for (int j = 0; j < NPAIR; ++j) {
        FP[j] = (v2f){0.0f, 0.0f}; FM[j] = (v2f){0.0f, 0.0f}; Z[j] = (v2f){0.0f, 0.0f};
    }
    Z[0].x = PD;

    float4* o4 = (float4*)(out + (size_t)p * NPULSES);
    float ebuf[4];

    static_for([&](auto tc) {
        constexpr int t = decltype(tc)::value;

        // echo: unscaled rotated F+_0 magnitude (E2/conj not folded in)
        float e = fmaf(c2, FP[0].x, fmaf(s2, FM[0].x, -sa * Z[0].x));
        ebuf[t & 3] = fabsf(e);
        if constexpr ((t & 3) == 3)
            o4[t >> 2] = make_float4(ebuf[0], ebuf[1], ebuf[2], ebuf[3]);

        if constexpr (t < NPULSES - 1) {
            constexpr int A  = cmin3(t, NSLOT - 1, (NPULSES - 1) - t);
            constexpr int JA = A >> 1;              // last pair rotated

            v2f RP[JA + 1], RM[JA + 1], ZN[JA + 1];
            static_for([&](auto jc) {
                constexpr int j = decltype(jc)::value;
                v2f CZ = Cc2 * Z[j];
                RP[j] = fma2(Aa2, FP[j], fma2(Bb2, FM[j], CZ));
                RM[j] = fma2(Bb2, FP[j], fma2(Aa2, FM[j], -CZ));
                ZN[j] = fma2(Ez2, Z[j], Dd2 * (FP[j] - FM[j]));
            }, std::make_integer_sequence<int, JA + 1>{});

            // fp shift: fp[k] = Rp[k-1] for k = MAXFP..1 (RP slots 0..MAXFP-1)
            constexpr int MAXFP = (A + 1 < NSLOT - 1) ? (A + 1) : (NSLOT - 1);
            static_for([&](auto kc) {
                constexpr int k = MAXFP - decltype(kc)::value;   // MAXFP..1
                constexpr int s = k - 1;
                float v = (s & 1) ? RP[s >> 1].y : RP[s >> 1].x;
                if constexpr (k & 1) FP[k >> 1].y = v; else FP[k >> 1].x = v;
            }, std::make_integer_sequence<int, MAXFP>{});

            // fm shift: fm[k] = Rm[k+1] for k = 0..MAXFM
            constexpr int MAXFM = (A & 1) ? (A - 1) : A;         // RM slot <= computed
            static_for([&](auto kc) {
                constexpr int k = decltype(kc)::value;           // 0..MAXFM
                constexpr int s = k + 1;
                float v = (s & 1) ? RM[s >> 1].y : RM[s >> 1].x;
                if constexpr (k & 1) FM[k >> 1].y = v; else FM[k >> 1].x = v;
            }, std::make_integer_sequence<int, MAXFM + 1>{});

            FP[0].x = RM[0].y;      // quirk: F+_0 and F-_0 both get Rm[1]

            static_for([&](auto jc) {
                constexpr int j = decltype(jc)::value;
                Z[j] = ZN[j];
            }, std::make_integer_sequence<int, JA + 1>{});
            Z[0].x += inj;
        }
    }, std::make_integer_sequence<int, NPULSES>{});
}

extern "C" void kernel_launch(void* const* d_in, const int* in_sizes, int n_in,
                              void* d_out, int out_size, void* d_ws, size_t ws_size,
                              hipStream_t stream) {
    const float* qm = (const float*)d_in[0];
    const int* tr = (const int*)d_in[2];   // d_in[1] = n_pulses (compile-time 32)
    float* out = (float*)d_out;
    int npix = in_sizes[0] / 3;

    int block = 256;
    int grid = (npix + block - 1) / block;
    epg_kernel<<<grid, block, 0, stream>>>(qm, tr, out, npix);
}